// Round 9
// baseline (369.436 us; speedup 1.0000x reference)
//
#include <hip/hip_runtime.h>
#include <stdint.h>

typedef __attribute__((ext_vector_type(4))) float f32x4;
typedef __attribute__((ext_vector_type(8))) __bf16 bf16x8;
typedef __attribute__((ext_vector_type(4))) __bf16 bf16x4;
typedef __attribute__((ext_vector_type(2))) __bf16 bf16x2;
typedef __attribute__((ext_vector_type(4))) short s16x4;
typedef __attribute__((ext_vector_type(4))) uint32_t u32x4;

#define MFMA16(a, b, c) __builtin_amdgcn_mfma_f32_16x16x32_bf16(a, b, c, 0, 0, 0)

#define B_ 4
#define S_ 2048
#define D_ 1024
#define H_ 16
#define NEG_ -1e10f
#define QSCALE 0.180336880f   // 0.125 * log2(e): softmax computed in exp2 domain
#define MNEG_ -100.0f         // masked score in exp2 domain: 2^-100 (bf16-normal, ~1e-30 rel)

// direct v_exp_f32 (D = 2^S0); __exp2f collides with glibc math.h on this toolchain
__device__ __forceinline__ float ex2(float x) { return __builtin_amdgcn_exp2f(x); }

__device__ __forceinline__ void glds16(const void* gsrc, void* ldst) {
  __builtin_amdgcn_global_load_lds(
      (__attribute__((address_space(1))) void*)(gsrc),
      (__attribute__((address_space(3))) void*)(ldst),
      16, 0, 0);
}

// pack a float pair to packed bf16 via vector init — fusion-friendly form so the
// compiler emits ONE v_cvt_pk_bf16_f32 (manual cast+shl+or form emitted 2 cvts + 2 bitops)
__device__ __forceinline__ uint32_t pack2(float a, float b) {
  bf16x2 v;
  v.x = (__bf16)a;
  v.y = (__bf16)b;
  return __builtin_bit_cast(uint32_t, v);
}

// ---------------- prep: converts + mask pack (round 9: mask 4 words/thread ILP) ----------------
// Round-7 rewrite verified (prep dropped out of top-5). Round 9: mask-pack gets 4
// consecutive words per thread (512 blocks): 32 independent int4 loads in flight and a
// single 16B bits store; all 4 words share one flags entry -> one rare atomicAnd.
__global__ __launch_bounds__(256) void prep(
    const float* __restrict__ xq, const float* __restrict__ xk, const float* __restrict__ xv,
    const float* __restrict__ wq, const float* __restrict__ wk, const float* __restrict__ wv,
    const float* __restrict__ wo,
    __bf16* __restrict__ oxq, __bf16* __restrict__ oxk, __bf16* __restrict__ oxv,
    __bf16* __restrict__ owq, __bf16* __restrict__ owk, __bf16* __restrict__ owv,
    __bf16* __restrict__ owo,
    const int* __restrict__ mask, uint32_t* __restrict__ bits, int* __restrict__ flags) {
  int bid = blockIdx.x, tid = threadIdx.x;
  if (bid < 1536) {  // X converts: 3 tensors x 512 blocks x 16 float4/thread (2M f4/tensor)
    int z = bid >> 9, local = bid & 511;
    const float* in = (z == 0) ? xq : (z == 1) ? xk : xv;
    __bf16* out = (z == 0) ? oxq : (z == 1) ? oxk : oxv;
    #pragma unroll
    for (int it = 0; it < 16; it++) {
      size_t i4 = (size_t)(local * 256 + tid) + (size_t)it * (512 * 256);
      float4 v = *(const float4*)(in + i4 * 4);
      bf16x4 o;
      o.x = (__bf16)v.x; o.y = (__bf16)v.y; o.z = (__bf16)v.z; o.w = (__bf16)v.w;
      *(bf16x4*)(out + i4 * 4) = o;
    }
  } else if (bid < 1792) {  // W converts: 4 tensors x 64 blocks x 16 float4/thread (256K f4)
    int m = bid - 1536;
    int z = m >> 6, local = m & 63;
    const float* in = (z == 0) ? wq : (z == 1) ? wk : (z == 2) ? wv : wo;
    __bf16* out = (z == 0) ? owq : (z == 1) ? owk : (z == 2) ? owv : owo;
    #pragma unroll
    for (int it = 0; it < 16; it++) {
      size_t i4 = (size_t)(local * 256 + tid) + (size_t)it * (64 * 256);
      float4 v = *(const float4*)(in + i4 * 4);
      bf16x4 o;
      o.x = (__bf16)v.x; o.y = (__bf16)v.y; o.z = (__bf16)v.z; o.w = (__bf16)v.w;
      *(bf16x4*)(out + i4 * 4) = o;
    }
  } else {  // mask pack: 512 blocks, 4 consecutive words (128 cols) per thread
    int wid4 = (bid - 1792) * 256 + tid;    // 131072 threads x 4 words = 524288 words
    int tt = wid4 & 15;                     // 128-col group = flags tt; words tt*4..tt*4+3
    int grow = wid4 >> 4;                   // b*2048 + srow
    const int* mp = mask + (size_t)grow * S_ + tt * 128;
    uint32_t wb[4] = {0, 0, 0, 0};
    #pragma unroll
    for (int wq2 = 0; wq2 < 4; wq2++)
      #pragma unroll
      for (int j = 0; j < 8; j++) {
        int4 mv = *(const int4*)(mp + wq2 * 32 + j * 4);
        wb[wq2] |= (mv.x != 0 ? 1u : 0u) << (j * 4);
        wb[wq2] |= (mv.y != 0 ? 1u : 0u) << (j * 4 + 1);
        wb[wq2] |= (mv.z != 0 ? 1u : 0u) << (j * 4 + 2);
        wb[wq2] |= (mv.w != 0 ? 1u : 0u) << (j * 4 + 3);
      }
    u32x4 st; st.x = wb[0]; st.y = wb[1]; st.z = wb[2]; st.w = wb[3];
    *(u32x4*)(&bits[(size_t)grow * 64 + tt * 4]) = st;   // 16B aligned (tt*4 words)
    if ((wb[0] & wb[1] & wb[2] & wb[3]) != 0xFFFFFFFFu) {
      int b = grow >> 11, srow = grow & 2047;
      atomicAnd(&flags[(b * 16 + (srow >> 7)) * 16 + tt], 0);
    }
  }
}

// ---------------- GEMM: acc[i][j] = dot(PA_row, PB_row), K=1024, BK=64 swizzled ----------------
// XCD-aware block swizzle (round 3): bijective remap so each XCD gets a contiguous by-range
// -> shared X tiles L2-resident per XCD. Structure is m97-complete (T1+T2+glds16+3/CU);
// unchanged this round (next lever would be the 8-phase template — race risk headlessly).
// MODE 0: z=0 q: PA=Wq PB=Xq -> qp [B,H,S,64] *QSCALE ; z=1 k likewise -> kp ;
//         z=2 v: PA=Xv PB=Wv -> vT [B,H,64,S]. All packed bf16x4 stores.
// MODE 1: PA=Wo PB=aout -> f32 out row-major [M,1024], float4 stores
template <int MODE>
__global__ __launch_bounds__(256, 3) void gemm_bt(
    const __bf16* __restrict__ A0, const __bf16* __restrict__ A1, const __bf16* __restrict__ A2,
    const __bf16* __restrict__ W0, const __bf16* __restrict__ W1, const __bf16* __restrict__ W2,
    void* O0, void* O1, void* O2) {
  const int K = 1024;
  // XCD swizzle within the 8x64 xy-plane (z offset is a multiple of 8 -> phase preserved)
  int lin = blockIdx.y * 8 + blockIdx.x;
  int swz = (lin & 7) * 64 + (lin >> 3);
  int bx = swz & 7, by = swz >> 3;

  const __bf16* PA; const __bf16* PB; void* O;
  int pa_t, pb_t;
  if (MODE == 0) {
    if (blockIdx.z == 0)      { PA = W0; PB = A0; O = O0; pa_t = bx; pb_t = by; }
    else if (blockIdx.z == 1) { PA = W1; PB = A1; O = O1; pa_t = bx; pb_t = by; }
    else                      { PA = A2; PB = W2; O = O2; pa_t = by; pb_t = bx; }
  } else { PA = W0; PB = A0; O = O0; pa_t = bx; pb_t = by; }

  __shared__ __align__(16) __bf16 As[128 * 64];
  __shared__ __align__(16) __bf16 Bs[128 * 64];
  int tid = threadIdx.x, lane = tid & 63, w = tid >> 6;
  int wm = w >> 1, wn = w & 1;
  int g = lane >> 4, l15 = lane & 15;
  f32x4 acc[4][4] = {};
  const __bf16* Ablk = PA + (size_t)(pa_t * 128) * K;
  const __bf16* Bblk = PB + (size_t)(pb_t * 128) * K;

  for (int kt = 0; kt < K; kt += 64) {
    __syncthreads();
    #pragma unroll
    for (int r = 0; r < 4; r++) {
      int C = r * 256 + tid;
      int row = C >> 3, c = C & 7;
      int c0 = c ^ (row & 7);
      glds16(Ablk + (size_t)row * K + kt + c0 * 8, (char*)As + C * 16);
      glds16(Bblk + (size_t)row * K + kt + c0 * 8, (char*)Bs + C * 16);
    }
    __syncthreads();
    #pragma unroll
    for (int kkq = 0; kkq < 2; kkq++) {
      bf16x8 af[4], bfr[4];
      #pragma unroll
      for (int i = 0; i < 4; i++) {
        int row = wm * 64 + i * 16 + l15;
        int ch = (kkq * 4 + g) ^ (row & 7);
        af[i] = *(const bf16x8*)((const char*)As + row * 128 + ch * 16);
      }
      #pragma unroll
      for (int j = 0; j < 4; j++) {
        int row = wn * 64 + j * 16 + l15;
        int ch = (kkq * 4 + g) ^ (row & 7);
        bfr[j] = *(const bf16x8*)((const char*)Bs + row * 128 + ch * 16);
      }
      #pragma unroll
      for (int i = 0; i < 4; i++)
        #pragma unroll
        for (int j = 0; j < 4; j++)
          acc[i][j] = MFMA16(af[i], bfr[j], acc[i][j]);
    }
  }

  if (MODE == 1) {
    // n = PA(Wo) rows (g*4+r contiguous), m = PB(aout) rows -> float4 stores
    #pragma unroll
    for (int i = 0; i < 4; i++)
      #pragma unroll
      for (int j = 0; j < 4; j++) {
        int n0 = pa_t * 128 + wm * 64 + i * 16 + g * 4;
        int m = pb_t * 128 + wn * 64 + j * 16 + l15;
        *(f32x4*)((float*)O + (size_t)m * 1024 + n0) = acc[i][j];
      }
  } else if (blockIdx.z == 2) {
    // v -> vT [B,H,64,S]; rows of PA are s, rows of PB are dv
    #pragma unroll
    for (int i = 0; i < 4; i++)
      #pragma unroll
      for (int j = 0; j < 4; j++) {
        int s0 = pa_t * 128 + wm * 64 + i * 16 + g * 4;
        int dvg = pb_t * 128 + wn * 64 + j * 16 + l15;
        int b = s0 >> 11, s = s0 & 2047;
        int h = dvg >> 6, dv = dvg & 63;
        bf16x4 o;
        #pragma unroll
        for (int r = 0; r < 4; r++) o[r] = (__bf16)acc[i][j][r];
        *(bf16x4*)((__bf16*)O + (((size_t)b * 16 + h) * 64 + dv) * 2048 + s) = o;
      }
  } else {
    // q/k -> [B,H,S,64]; rows of PA are dk, rows of PB are s
    float scale = (blockIdx.z == 0) ? QSCALE : 1.0f;
    #pragma unroll
    for (int i = 0; i < 4; i++)
      #pragma unroll
      for (int j = 0; j < 4; j++) {
        int dkg = pa_t * 128 + wm * 64 + i * 16 + g * 4;
        int sg = pb_t * 128 + wn * 64 + j * 16 + l15;
        int h = dkg >> 6, dk = dkg & 63;
        int b = sg >> 11, s = sg & 2047;
        bf16x4 o;
        #pragma unroll
        for (int r = 0; r < 4; r++) o[r] = (__bf16)(acc[i][j][r] * scale);
        *(bf16x4*)((__bf16*)O + (((size_t)b * 16 + h) * 2048 + s) * 64 + dk) = o;
      }
  }
}

// ---------------- flash attention (S^T formulation, exp2 domain, K=32 MFMA PV) ----------------
// Round 9 (on the round-8 verified K=32-PV structure): (a) pack via bf16x2 vector init ->
// single v_cvt_pk_bf16_f32 per pair (was 2 cvts + shl + or: ~48 extra VALU/kt on a
// 50%-VALUBusy kernel); (b) V source addresses hoisted out of the loop (kt-invariant
// except +kt*128B). Carried (counter-verified): KVBLK=64 4 blocks/CU, K=32 PV with
// column-permuted V (MfmaUtil 54->38 at -10us), no-online-max exp2 numerics, XCD swizzle,
// conflict-free swizzles, one vmcnt(0)+barrier per kt, loads-before-compute, ones-MFMA
// row-sum, zero4 C-init, setprio.
__global__ __launch_bounds__(256, 4) void attn(
    const __bf16* __restrict__ qp, const __bf16* __restrict__ kp,
    const __bf16* __restrict__ vt_, __bf16* __restrict__ aout,
    const uint32_t* __restrict__ bits, const int* __restrict__ flags) {
  // XCD swizzle: lin%8 = XCD -> give each XCD a contiguous bh range (16 qt x 8 bh)
  int lin = blockIdx.y * 16 + blockIdx.x;
  int swz = (lin & 7) * 128 + (lin >> 3);
  int qt = swz & 15, bh = swz >> 4;
  int b = bh >> 4, h = bh & 15;
  int tid = threadIdx.x, lane = tid & 63, w = tid >> 6;
  int g = lane >> 4, l15 = lane & 15;

  // buf p (p=0,1): K at smem+p*16384 [64 kcol][64 dk] chunk-swizzled bf16 (8KB),
  //                V at smem+p*16384+8192 [64 dv][64 kcol] column-permuted+swizzled (8KB)
  __shared__ __align__(16) char smem[32768];

  const __bf16* Qg = qp + ((size_t)bh * S_ + qt * 128) * 64;
  const __bf16* Kg = kp + (size_t)bh * S_ * 64;
  const __bf16* Vg = vt_ + (size_t)bh * 64 * S_;

  // stage Q (swizzled [128][64] = 16KB, spans buf0 K+V regions; consumed before loop)
  #pragma unroll
  for (int r = 0; r < 4; r++) {
    int C = r * 256 + tid;
    int row = C >> 3, c = C & 7, c0 = c ^ (row & 7);
    glds16(Qg + row * 64 + c0 * 8, smem + C * 16);
  }
  __syncthreads();
  bf16x8 qf[2][2];  // Q[qrow=w*32+i*16+l15][dk=kkq*32+g*8+j]
  #pragma unroll
  for (int i = 0; i < 2; i++)
    #pragma unroll
    for (int kkq = 0; kkq < 2; kkq++) {
      int row = w * 32 + i * 16 + l15;
      int ch = (kkq * 4 + g) ^ (row & 7);
      qf[i][kkq] = *(const bf16x8*)(smem + row * 128 + ch * 16);
    }
  __syncthreads();

  // hoisted per-thread staging addresses (kt-invariant parts)
  const __bf16* ksrc[2];
  int kdst[2];
  const __bf16* vsrc[2];
  #pragma unroll
  for (int r = 0; r < 2; r++) {
    int C = r * 256 + tid;
    // K: 16B chunk-XOR swizzle
    int krow = C >> 3, kc = C & 7, kc0 = kc ^ (krow & 7);
    ksrc[r] = Kg + (size_t)krow * 64 + kc0 * 8;
    kdst[r] = C * 16;
    // V: stored chunk sc holds pre-swizzle chunk p16 = sc^(row&7) = (t2,g4);
    // content = [kcols 32t2+4g4.. | 32t2+16+4g4..] (column permutation pi)
    int vrow = C >> 3, vsc = C & 7;
    int p16 = vsc ^ (vrow & 7);
    int t2 = p16 >> 2, g4 = p16 & 3;
    vsrc[r] = Vg + (size_t)vrow * S_ + t2 * 32 + g4 * 4;
  }

  // K stage: 2 glds16 into buffer p
  auto stageK = [&](int kt2, int p) {
    char* Kl = smem + p * 16384;
    #pragma unroll
    for (int r = 0; r < 2; r++)
      glds16(ksrc[r] + (size_t)kt2 * 64 * 64, Kl + kdst[r]);
  };
  // V load to regs (2x8B pairs from permuted addresses)
  auto loadV = [&](int kt2, int4* vreg) {
    #pragma unroll
    for (int r = 0; r < 2; r++) {
      const __bf16* src = vsrc[r] + kt2 * 64;
      int2 lo = *(const int2*)(src);
      int2 hi = *(const int2*)(src + 16);
      int4 v; v.x = lo.x; v.y = lo.y; v.z = hi.x; v.w = hi.y;
      vreg[r] = v;
    }
  };
  // V write: linear ds_write_b128 (permutation+swizzle already applied via source addr)
  auto writeV = [&](int p, const int4* vreg) {
    char* Vl = smem + p * 16384 + 8192;
    #pragma unroll
    for (int r = 0; r < 2; r++) {
      int C = r * 256 + tid;
      *(int4*)(Vl + C * 16) = vreg[r];
    }
  };

  f32x4 oacc[4][2] = {};   // O^T[dv=vt*16+g*4+r][qrow=w*32+i*16+l15]
  f32x4 sumacc[2] = {};    // row-sum of P via ones-MFMA (replicated over r, col=own qrow)
  const f32x4 zero4 = {0.f, 0.f, 0.f, 0.f};                     // persistent MFMA C-init
  const u32x4 ones_u = {0x3F803F80u, 0x3F803F80u, 0x3F803F80u, 0x3F803F80u};
  const bf16x8 ones8 = __builtin_bit_cast(bf16x8, ones_u);      // 8 x bf16 1.0

  int4 vreg[2];

  // prologue: fill buf0 with kt=0
  stageK(0, 0);
  loadV(0, vreg);
  asm volatile("s_waitcnt vmcnt(0)" ::: "memory");
  writeV(0, vreg);
  asm volatile("s_waitcnt lgkmcnt(0)" ::: "memory");
  __builtin_amdgcn_s_barrier();
  __builtin_amdgcn_sched_barrier(0);

  for (int kt = 0; kt < 32; kt++) {
    int cur = kt & 1;
    // issue next tile's loads FIRST — they fly under this tile's compute
    if (kt + 1 < 32) {
      stageK(kt + 1, cur ^ 1);
      loadV(kt + 1, vreg);
    }
    __builtin_amdgcn_sched_barrier(0);  // pin load issue before compute

    const char* Klds = smem + cur * 16384;
    const char* Vlds = Klds + 8192;
    int fl = flags[(b * 16 + qt) * 16 + (kt >> 1)];

    // S^T = K * Q^T ; sacc[i][jt]: kcol=jt*16+g*4+r, qrow=w*32+i*16+l15
    f32x4 sacc[2][4];
    __builtin_amdgcn_s_setprio(1);
    #pragma unroll
    for (int jt = 0; jt < 4; jt++) {
      int row = jt * 16 + l15;
      bf16x8 kf0 = *(const bf16x8*)(Klds + row * 128 + (g ^ (row & 7)) * 16);
      bf16x8 kf1 = *(const bf16x8*)(Klds + row * 128 + ((4 + g) ^ (row & 7)) * 16);
      sacc[0][jt] = MFMA16(kf0, qf[0][0], zero4);
      sacc[0][jt] = MFMA16(kf1, qf[0][1], sacc[0][jt]);
      sacc[1][jt] = MFMA16(kf0, qf[1][0], zero4);
      sacc[1][jt] = MFMA16(kf1, qf[1][1], sacc[1][jt]);
    }
    __builtin_amdgcn_s_setprio(0);

    if (!fl) {  // exact masking slow path: masked score -> -100 (2^-100 after exp2)
      #pragma unroll
      for (int i = 0; i < 2; i++) {
        int srow = qt * 128 + w * 32 + i * 16 + l15;
        const uint32_t* bw = &bits[((size_t)b * S_ + srow) * 64 + kt * 2];
        uint32_t mw[2] = {bw[0], bw[1]};
        #pragma unroll
        for (int jt = 0; jt < 4; jt++)
          #pragma unroll
          for (int r = 0; r < 4; r++) {
            int bitpos = (jt & 1) * 16 + g * 4 + r;
            if (!((mw[jt >> 1] >> bitpos) & 1)) sacc[i][jt][r] = MNEG_;
          }
      }
    }

    // per 32-col block t2: exp2 -> cvt_pk pack [jt=2t2 | jt=2t2+1] -> K=32 PV MFMA + sum
    #pragma unroll
    for (int t2 = 0; t2 < 2; t2++) {
      bf16x8 pf[2];
      #pragma unroll
      for (int i = 0; i < 2; i++) {
        float a0 = ex2(sacc[i][2 * t2][0]);
        float a1 = ex2(sacc[i][2 * t2][1]);
        float a2 = ex2(sacc[i][2 * t2][2]);
        float a3 = ex2(sacc[i][2 * t2][3]);
        float b0 = ex2(sacc[i][2 * t2 + 1][0]);
        float b1 = ex2(sacc[i][2 * t2 + 1][1]);
        float b2 = ex2(sacc[i][2 * t2 + 1][2]);
        float b3 = ex2(sacc[i][2 * t2 + 1][3]);
        u32x4 t;
        t.x = pack2(a0, a1);
        t.y = pack2(a2, a3);
        t.z = pack2(b0, b1);
        t.w = pack2(b2, b3);
        pf[i] = __builtin_bit_cast(bf16x8, t);
      }
      __builtin_amdgcn_s_setprio(1);
      #pragma unroll
      for (int vt = 0; vt < 4; vt++) {
        int row = vt * 16 + l15;
        int c16 = (t2 * 4 + g) ^ (row & 7);
        bf16x8 vv = *(const bf16x8*)(Vlds + row * 128 + c16 * 16);
        oacc[vt][0] = MFMA16(vv, pf[0], oacc[vt][0]);
        oacc[vt][1] = MFMA16(vv, pf[1], oacc[vt][1]);
      }
      sumacc[0] = MFMA16(ones8, pf[0], sumacc[0]);
      sumacc[1] = MFMA16(ones8, pf[1], sumacc[1]);
      __builtin_amdgcn_s_setprio(0);
    }

    // drain global loads (issued ~1000cy ago), commit V regs to next buffer, ONE barrier
    asm volatile("s_waitcnt vmcnt(0)" ::: "memory");
    if (kt + 1 < 32) writeV(cur ^ 1, vreg);
    asm volatile("s_waitcnt lgkmcnt(0)" ::: "memory");
    __builtin_amdgcn_s_barrier();
    __builtin_amdgcn_sched_barrier(0);
  }

  // epilogue: O^T / l -> attn_out [B,S,H*64] bf16 (sumacc replicated over r; col = own qrow)
  #pragma unroll
  for (int i = 0; i < 2; i++) {
    float inv = 1.0f / sumacc[i][0];
    int srow = qt * 128 + w * 32 + i * 16 + l15;
    #pragma unroll
    for (int vt = 0; vt < 4; vt++) {
      bf16x4 o;
      #pragma unroll
      for (int r = 0; r < 4; r++) o[r] = (__bf16)(oacc[vt][i][r] * inv);
      *(bf16x4*)(aout + ((size_t)b * S_ + srow) * 1024 + h * 64 + vt * 16 + g * 4) = o;
    }
  }
}

// ---------------- launch ----------------
extern "C" void kernel_launch(void* const* d_in, const int* in_sizes, int n_in,
                              void* d_out, int out_size, void* d_ws, size_t ws_size,
                              hipStream_t stream) {
  const float* queries = (const float*)d_in[0];
  const float* keys    = (const float*)d_in[1];
  const float* values  = (const float*)d_in[2];
  const int*   mask    = (const int*)d_in[3];
  const float* Wq      = (const float*)d_in[4];
  const float* Wk      = (const float*)d_in[5];
  const float* Wv      = (const float*)d_in[6];
  const float* Wo      = (const float*)d_in[7];

  char* ws = (char*)d_ws;
  __bf16* Xq  = (__bf16*)(ws + 0);          // 16 MB, later reused as attn_out
  __bf16* Xk  = (__bf16*)(ws + 16777216);   // 16 MB
  __bf16* Xv  = (__bf16*)(ws + 33554432);   // 16 MB
  __bf16* Wqb = (__bf16*)(ws + 50331648);   // 2 MB each
  __bf16* Wkb = (__bf16*)(ws + 52428800);
  __bf16* Wvb = (__bf16*)(ws + 54525952);
  __bf16* Wob = (__bf16*)(ws + 56623104);
  __bf16* qp  = (__bf16*)(ws + 58720256);   // 16 MB [B,H,S,64]
  __bf16* kp  = (__bf16*)(ws + 75497472);   // 16 MB [B,H,S,64]
  __bf16* vT  = (__bf16*)(ws + 92274688);   // 16 MB [B,H,64,S]
  uint32_t* bits = (uint32_t*)(ws + 109051904);  // 2 MB
  int* flags     = (int*)(ws + 111149056);       // 4 KB
  __bf16* aout = Xq;  // alias: Xq dead after proj GEMM

  // flags pre-init to all-ones (0xFFFFFFFF truthy for attn's `if(!fl)`); prep atomicAnds 0
  hipMemsetAsync(flags, 0xFF, 4096, stream);

  prep<<<2304, 256, 0, stream>>>(queries, keys, values, Wq, Wk, Wv, Wo,
                                 Xq, Xk, Xv, Wqb, Wkb, Wvb, Wob,
                                 mask, bits, flags);

  gemm_bt<0><<<dim3(8, 64, 3), 256, 0, stream>>>(Xq, Xk, Xv, Wqb, Wkb, Wvb,
                                                 (void*)qp, (void*)kp, (void*)vT);

  attn<<<dim3(16, 64), 256, 0, stream>>>(qp, kp, vT, aout, bits, flags);

  gemm_bt<1><<<dim3(8, 64, 1), 256, 0, stream>>>(aout, nullptr, nullptr, Wob, nullptr, nullptr,
                                                 (void*)d_out, nullptr, nullptr);
}

// Round 10
// 350.899 us; speedup vs baseline: 1.0528x; 1.0528x over previous
//
#include <hip/hip_runtime.h>
#include <stdint.h>

typedef __attribute__((ext_vector_type(4))) float f32x4;
typedef __attribute__((ext_vector_type(8))) __bf16 bf16x8;
typedef __attribute__((ext_vector_type(4))) __bf16 bf16x4;
typedef __attribute__((ext_vector_type(2))) __bf16 bf16x2;
typedef __attribute__((ext_vector_type(4))) uint32_t u32x4;

#define MFMA16(a, b, c) __builtin_amdgcn_mfma_f32_16x16x32_bf16(a, b, c, 0, 0, 0)

#define B_ 4
#define S_ 2048
#define D_ 1024
#define H_ 16
#define NEG_ -1e10f
#define QSCALE 0.180336880f   // 0.125 * log2(e): softmax computed in exp2 domain
#define MNEG_ -100.0f         // masked score in exp2 domain: 2^-100 (bf16-normal, ~1e-30 rel)

// direct v_exp_f32 (D = 2^S0); __exp2f collides with glibc math.h on this toolchain
__device__ __forceinline__ float ex2(float x) { return __builtin_amdgcn_exp2f(x); }

__device__ __forceinline__ void glds16(const void* gsrc, void* ldst) {
  __builtin_amdgcn_global_load_lds(
      (__attribute__((address_space(1))) void*)(gsrc),
      (__attribute__((address_space(3))) void*)(ldst),
      16, 0, 0);
}

// pack a float pair to packed bf16 via vector init — fusion-friendly form so the
// compiler emits ONE v_cvt_pk_bf16_f32 (manual cast+shl+or form emitted 2 cvts + 2 bitops)
__device__ __forceinline__ uint32_t pack2(float a, float b) {
  bf16x2 v;
  v.x = (__bf16)a;
  v.y = (__bf16)b;
  return __builtin_bit_cast(uint32_t, v);
}

// ---------------- prep: converts + mask pack (round 10: ballot-register mask pack) -------------
// Round-9 post-mortem: mask phase was the prep defect (4 words/thread -> 512B lane stride,
// 64 lines / 32KB touched per wave-instr = L1 thrash; ~1.5 TB/s). Round 10: one WAVE per
// mask row — lane l loads cols {l, l+64, ..., l+31*64}: 32 independent perfectly-coalesced
// 256B loads (all in flight), then 32 register ballots; lane k keeps ballot k's word pair;
// lanes 0-31 store one uint2 = contiguous 256B per row. Per-tt exact flags via wave-uniform
// failmask (bal != ~0 -> fail |= 1<<(k>>1)), predicated atomicAnd per failing tt (never
// fires for all-ones). Bit order unchanged: bit j of word w = col w*32+j.
__global__ __launch_bounds__(256) void prep(
    const float* __restrict__ xq, const float* __restrict__ xk, const float* __restrict__ xv,
    const float* __restrict__ wq, const float* __restrict__ wk, const float* __restrict__ wv,
    const float* __restrict__ wo,
    __bf16* __restrict__ oxq, __bf16* __restrict__ oxk, __bf16* __restrict__ oxv,
    __bf16* __restrict__ owq, __bf16* __restrict__ owk, __bf16* __restrict__ owv,
    __bf16* __restrict__ owo,
    const int* __restrict__ mask, uint32_t* __restrict__ bits, int* __restrict__ flags) {
  int bid = blockIdx.x, tid = threadIdx.x;
  if (bid < 1536) {  // X converts: 3 tensors x 512 blocks x 16 float4/thread (2M f4/tensor)
    int z = bid >> 9, local = bid & 511;
    const float* in = (z == 0) ? xq : (z == 1) ? xk : xv;
    __bf16* out = (z == 0) ? oxq : (z == 1) ? oxk : oxv;
    #pragma unroll
    for (int it = 0; it < 16; it++) {
      size_t i4 = (size_t)(local * 256 + tid) + (size_t)it * (512 * 256);
      float4 v = *(const float4*)(in + i4 * 4);
      bf16x4 o;
      o.x = (__bf16)v.x; o.y = (__bf16)v.y; o.z = (__bf16)v.z; o.w = (__bf16)v.w;
      *(bf16x4*)(out + i4 * 4) = o;
    }
  } else if (bid < 1792) {  // W converts: 4 tensors x 64 blocks x 16 float4/thread (256K f4)
    int m = bid - 1536;
    int z = m >> 6, local = m & 63;
    const float* in = (z == 0) ? wq : (z == 1) ? wk : (z == 2) ? wv : wo;
    __bf16* out = (z == 0) ? owq : (z == 1) ? owk : (z == 2) ? owv : owo;
    #pragma unroll
    for (int it = 0; it < 16; it++) {
      size_t i4 = (size_t)(local * 256 + tid) + (size_t)it * (64 * 256);
      float4 v = *(const float4*)(in + i4 * 4);
      bf16x4 o;
      o.x = (__bf16)v.x; o.y = (__bf16)v.y; o.z = (__bf16)v.z; o.w = (__bf16)v.w;
      *(bf16x4*)(out + i4 * 4) = o;
    }
  } else {  // mask pack: 2048 blocks x 4 waves; one wave per row (8192 rows = B*S)
    int wv = tid >> 6, lane = tid & 63;
    int grow = (bid - 1792) * 4 + wv;       // b*2048 + srow
    const int* mp = mask + (size_t)grow * S_;
    int vals[32];
    #pragma unroll
    for (int k = 0; k < 32; k++) vals[k] = mp[k * 64 + lane];  // coalesced, all in flight
    uint32_t w0 = 0, w1 = 0;   // lane k (k<32) keeps ballot k's words 2k, 2k+1
    uint32_t fail = 0;         // wave-uniform per-tt failmask (tt = k>>1)
    #pragma unroll
    for (int k = 0; k < 32; k++) {
      unsigned long long bal = __ballot(vals[k] != 0);
      if (bal != ~0ull) fail |= 1u << (k >> 1);
      if (lane == k) { w0 = (uint32_t)bal; w1 = (uint32_t)(bal >> 32); }
    }
    if (lane < 32) {
      uint2 st; st.x = w0; st.y = w1;
      *(uint2*)(&bits[(size_t)grow * 64 + lane * 2]) = st;  // contiguous 256B per row
    }
    if (fail && lane < 16 && ((fail >> lane) & 1)) {
      int b = grow >> 11, srow = grow & 2047;
      atomicAnd(&flags[(b * 16 + (srow >> 7)) * 16 + lane], 0);
    }
  }
}

// ---------------- GEMM: acc[i][j] = dot(PA_row, PB_row), K=1024, BK=64 swizzled ----------------
// XCD-aware block swizzle (round 3): bijective remap so each XCD gets a contiguous by-range
// -> shared X tiles L2-resident per XCD. Structure is m97-complete (T1+T2+glds16+3/CU);
// unchanged (next lever would be the 8-phase template — race risk headlessly).
// MODE 0: z=0 q: PA=Wq PB=Xq -> qp [B,H,S,64] *QSCALE ; z=1 k likewise -> kp ;
//         z=2 v: PA=Xv PB=Wv -> vT [B,H,64,S]. All packed bf16x4 stores.
// MODE 1: PA=Wo PB=aout -> f32 out row-major [M,1024], float4 stores
template <int MODE>
__global__ __launch_bounds__(256, 3) void gemm_bt(
    const __bf16* __restrict__ A0, const __bf16* __restrict__ A1, const __bf16* __restrict__ A2,
    const __bf16* __restrict__ W0, const __bf16* __restrict__ W1, const __bf16* __restrict__ W2,
    void* O0, void* O1, void* O2) {
  const int K = 1024;
  // XCD swizzle within the 8x64 xy-plane (z offset is a multiple of 8 -> phase preserved)
  int lin = blockIdx.y * 8 + blockIdx.x;
  int swz = (lin & 7) * 64 + (lin >> 3);
  int bx = swz & 7, by = swz >> 3;

  const __bf16* PA; const __bf16* PB; void* O;
  int pa_t, pb_t;
  if (MODE == 0) {
    if (blockIdx.z == 0)      { PA = W0; PB = A0; O = O0; pa_t = bx; pb_t = by; }
    else if (blockIdx.z == 1) { PA = W1; PB = A1; O = O1; pa_t = bx; pb_t = by; }
    else                      { PA = A2; PB = W2; O = O2; pa_t = by; pb_t = bx; }
  } else { PA = W0; PB = A0; O = O0; pa_t = bx; pb_t = by; }

  __shared__ __align__(16) __bf16 As[128 * 64];
  __shared__ __align__(16) __bf16 Bs[128 * 64];
  int tid = threadIdx.x, lane = tid & 63, w = tid >> 6;
  int wm = w >> 1, wn = w & 1;
  int g = lane >> 4, l15 = lane & 15;
  f32x4 acc[4][4] = {};
  const __bf16* Ablk = PA + (size_t)(pa_t * 128) * K;
  const __bf16* Bblk = PB + (size_t)(pb_t * 128) * K;

  for (int kt = 0; kt < K; kt += 64) {
    __syncthreads();
    #pragma unroll
    for (int r = 0; r < 4; r++) {
      int C = r * 256 + tid;
      int row = C >> 3, c = C & 7;
      int c0 = c ^ (row & 7);
      glds16(Ablk + (size_t)row * K + kt + c0 * 8, (char*)As + C * 16);
      glds16(Bblk + (size_t)row * K + kt + c0 * 8, (char*)Bs + C * 16);
    }
    __syncthreads();
    #pragma unroll
    for (int kkq = 0; kkq < 2; kkq++) {
      bf16x8 af[4], bfr[4];
      #pragma unroll
      for (int i = 0; i < 4; i++) {
        int row = wm * 64 + i * 16 + l15;
        int ch = (kkq * 4 + g) ^ (row & 7);
        af[i] = *(const bf16x8*)((const char*)As + row * 128 + ch * 16);
      }
      #pragma unroll
      for (int j = 0; j < 4; j++) {
        int row = wn * 64 + j * 16 + l15;
        int ch = (kkq * 4 + g) ^ (row & 7);
        bfr[j] = *(const bf16x8*)((const char*)Bs + row * 128 + ch * 16);
      }
      #pragma unroll
      for (int i = 0; i < 4; i++)
        #pragma unroll
        for (int j = 0; j < 4; j++)
          acc[i][j] = MFMA16(af[i], bfr[j], acc[i][j]);
    }
  }

  if (MODE == 1) {
    // n = PA(Wo) rows (g*4+r contiguous), m = PB(aout) rows -> float4 stores
    #pragma unroll
    for (int i = 0; i < 4; i++)
      #pragma unroll
      for (int j = 0; j < 4; j++) {
        int n0 = pa_t * 128 + wm * 64 + i * 16 + g * 4;
        int m = pb_t * 128 + wn * 64 + j * 16 + l15;
        *(f32x4*)((float*)O + (size_t)m * 1024 + n0) = acc[i][j];
      }
  } else if (blockIdx.z == 2) {
    // v -> vT [B,H,64,S]; rows of PA are s, rows of PB are dv
    #pragma unroll
    for (int i = 0; i < 4; i++)
      #pragma unroll
      for (int j = 0; j < 4; j++) {
        int s0 = pa_t * 128 + wm * 64 + i * 16 + g * 4;
        int dvg = pb_t * 128 + wn * 64 + j * 16 + l15;
        int b = s0 >> 11, s = s0 & 2047;
        int h = dvg >> 6, dv = dvg & 63;
        bf16x4 o;
        #pragma unroll
        for (int r = 0; r < 4; r++) o[r] = (__bf16)acc[i][j][r];
        *(bf16x4*)((__bf16*)O + (((size_t)b * 16 + h) * 64 + dv) * 2048 + s) = o;
      }
  } else {
    // q/k -> [B,H,S,64]; rows of PA are dk, rows of PB are s
    float scale = (blockIdx.z == 0) ? QSCALE : 1.0f;
    #pragma unroll
    for (int i = 0; i < 4; i++)
      #pragma unroll
      for (int j = 0; j < 4; j++) {
        int dkg = pa_t * 128 + wm * 64 + i * 16 + g * 4;
        int sg = pb_t * 128 + wn * 64 + j * 16 + l15;
        int h = dkg >> 6, dk = dkg & 63;
        int b = sg >> 11, s = sg & 2047;
        bf16x4 o;
        #pragma unroll
        for (int r = 0; r < 4; r++) o[r] = (__bf16)(acc[i][j][r] * scale);
        *(bf16x4*)((__bf16*)O + (((size_t)b * 16 + h) * 2048 + s) * 64 + dk) = o;
      }
  }
}

// ---------------- flash attention (S^T formulation, exp2 domain, K=32 MFMA PV) ----------------
// Round 9 verified (attn <83.3us, out of top-5): pack2 cvt_pk fusion + hoisted V addresses.
// Carried (counter-verified): KVBLK=64 4 blocks/CU, K=32 PV with column-permuted V
// (MfmaUtil 54->38 at -10us), no-online-max exp2 numerics, XCD swizzle, conflict-free
// swizzles, one vmcnt(0)+barrier per kt, loads-before-compute, ones-MFMA row-sum,
// zero4 C-init, setprio. Unchanged this round.
__global__ __launch_bounds__(256, 4) void attn(
    const __bf16* __restrict__ qp, const __bf16* __restrict__ kp,
    const __bf16* __restrict__ vt_, __bf16* __restrict__ aout,
    const uint32_t* __restrict__ bits, const int* __restrict__ flags) {
  // XCD swizzle: lin%8 = XCD -> give each XCD a contiguous bh range (16 qt x 8 bh)
  int lin = blockIdx.y * 16 + blockIdx.x;
  int swz = (lin & 7) * 128 + (lin >> 3);
  int qt = swz & 15, bh = swz >> 4;
  int b = bh >> 4, h = bh & 15;
  int tid = threadIdx.x, lane = tid & 63, w = tid >> 6;
  int g = lane >> 4, l15 = lane & 15;

  // buf p (p=0,1): K at smem+p*16384 [64 kcol][64 dk] chunk-swizzled bf16 (8KB),
  //                V at smem+p*16384+8192 [64 dv][64 kcol] column-permuted+swizzled (8KB)
  __shared__ __align__(16) char smem[32768];

  const __bf16* Qg = qp + ((size_t)bh * S_ + qt * 128) * 64;
  const __bf16* Kg = kp + (size_t)bh * S_ * 64;
  const __bf16* Vg = vt_ + (size_t)bh * 64 * S_;

  // stage Q (swizzled [128][64] = 16KB, spans buf0 K+V regions; consumed before loop)
  #pragma unroll
  for (int r = 0; r < 4; r++) {
    int C = r * 256 + tid;
    int row = C >> 3, c = C & 7, c0 = c ^ (row & 7);
    glds16(Qg + row * 64 + c0 * 8, smem + C * 16);
  }
  __syncthreads();
  bf16x8 qf[2][2];  // Q[qrow=w*32+i*16+l15][dk=kkq*32+g*8+j]
  #pragma unroll
  for (int i = 0; i < 2; i++)
    #pragma unroll
    for (int kkq = 0; kkq < 2; kkq++) {
      int row = w * 32 + i * 16 + l15;
      int ch = (kkq * 4 + g) ^ (row & 7);
      qf[i][kkq] = *(const bf16x8*)(smem + row * 128 + ch * 16);
    }
  __syncthreads();

  // hoisted per-thread staging addresses (kt-invariant parts)
  const __bf16* ksrc[2];
  int kdst[2];
  const __bf16* vsrc[2];
  #pragma unroll
  for (int r = 0; r < 2; r++) {
    int C = r * 256 + tid;
    // K: 16B chunk-XOR swizzle
    int krow = C >> 3, kc = C & 7, kc0 = kc ^ (krow & 7);
    ksrc[r] = Kg + (size_t)krow * 64 + kc0 * 8;
    kdst[r] = C * 16;
    // V: stored chunk sc holds pre-swizzle chunk p16 = sc^(row&7) = (t2,g4);
    // content = [kcols 32t2+4g4.. | 32t2+16+4g4..] (column permutation pi)
    int vrow = C >> 3, vsc = C & 7;
    int p16 = vsc ^ (vrow & 7);
    int t2 = p16 >> 2, g4 = p16 & 3;
    vsrc[r] = Vg + (size_t)vrow * S_ + t2 * 32 + g4 * 4;
  }

  // K stage: 2 glds16 into buffer p
  auto stageK = [&](int kt2, int p) {
    char* Kl = smem + p * 16384;
    #pragma unroll
    for (int r = 0; r < 2; r++)
      glds16(ksrc[r] + (size_t)kt2 * 64 * 64, Kl + kdst[r]);
  };
  // V load to regs (2x8B pairs from permuted addresses)
  auto loadV = [&](int kt2, int4* vreg) {
    #pragma unroll
    for (int r = 0; r < 2; r++) {
      const __bf16* src = vsrc[r] + kt2 * 64;
      int2 lo = *(const int2*)(src);
      int2 hi = *(const int2*)(src + 16);
      int4 v; v.x = lo.x; v.y = lo.y; v.z = hi.x; v.w = hi.y;
      vreg[r] = v;
    }
  };
  // V write: linear ds_write_b128 (permutation+swizzle already applied via source addr)
  auto writeV = [&](int p, const int4* vreg) {
    char* Vl = smem + p * 16384 + 8192;
    #pragma unroll
    for (int r = 0; r < 2; r++) {
      int C = r * 256 + tid;
      *(int4*)(Vl + C * 16) = vreg[r];
    }
  };

  f32x4 oacc[4][2] = {};   // O^T[dv=vt*16+g*4+r][qrow=w*32+i*16+l15]
  f32x4 sumacc[2] = {};    // row-sum of P via ones-MFMA (replicated over r, col=own qrow)
  const f32x4 zero4 = {0.f, 0.f, 0.f, 0.f};                     // persistent MFMA C-init
  const u32x4 ones_u = {0x3F803F80u, 0x3F803F80u, 0x3F803F80u, 0x3F803F80u};
  const bf16x8 ones8 = __builtin_bit_cast(bf16x8, ones_u);      // 8 x bf16 1.0

  int4 vreg[2];

  // prologue: fill buf0 with kt=0
  stageK(0, 0);
  loadV(0, vreg);
  asm volatile("s_waitcnt vmcnt(0)" ::: "memory");
  writeV(0, vreg);
  asm volatile("s_waitcnt lgkmcnt(0)" ::: "memory");
  __builtin_amdgcn_s_barrier();
  __builtin_amdgcn_sched_barrier(0);

  for (int kt = 0; kt < 32; kt++) {
    int cur = kt & 1;
    // issue next tile's loads FIRST — they fly under this tile's compute
    if (kt + 1 < 32) {
      stageK(kt + 1, cur ^ 1);
      loadV(kt + 1, vreg);
    }
    __builtin_amdgcn_sched_barrier(0);  // pin load issue before compute

    const char* Klds = smem + cur * 16384;
    const char* Vlds = Klds + 8192;
    int fl = flags[(b * 16 + qt) * 16 + (kt >> 1)];

    // S^T = K * Q^T ; sacc[i][jt]: kcol=jt*16+g*4+r, qrow=w*32+i*16+l15
    f32x4 sacc[2][4];
    __builtin_amdgcn_s_setprio(1);
    #pragma unroll
    for (int jt = 0; jt < 4; jt++) {
      int row = jt * 16 + l15;
      bf16x8 kf0 = *(const bf16x8*)(Klds + row * 128 + (g ^ (row & 7)) * 16);
      bf16x8 kf1 = *(const bf16x8*)(Klds + row * 128 + ((4 + g) ^ (row & 7)) * 16);
      sacc[0][jt] = MFMA16(kf0, qf[0][0], zero4);
      sacc[0][jt] = MFMA16(kf1, qf[0][1], sacc[0][jt]);
      sacc[1][jt] = MFMA16(kf0, qf[1][0], zero4);
      sacc[1][jt] = MFMA16(kf1, qf[1][1], sacc[1][jt]);
    }
    __builtin_amdgcn_s_setprio(0);

    if (!fl) {  // exact masking slow path: masked score -> -100 (2^-100 after exp2)
      #pragma unroll
      for (int i = 0; i < 2; i++) {
        int srow = qt * 128 + w * 32 + i * 16 + l15;
        const uint32_t* bw = &bits[((size_t)b * S_ + srow) * 64 + kt * 2];
        uint32_t mw[2] = {bw[0], bw[1]};
        #pragma unroll
        for (int jt = 0; jt < 4; jt++)
          #pragma unroll
          for (int r = 0; r < 4; r++) {
            int bitpos = (jt & 1) * 16 + g * 4 + r;
            if (!((mw[jt >> 1] >> bitpos) & 1)) sacc[i][jt][r] = MNEG_;
          }
      }
    }

    // per 32-col block t2: exp2 -> cvt_pk pack [jt=2t2 | jt=2t2+1] -> K=32 PV MFMA + sum
    #pragma unroll
    for (int t2 = 0; t2 < 2; t2++) {
      bf16x8 pf[2];
      #pragma unroll
      for (int i = 0; i < 2; i++) {
        float a0 = ex2(sacc[i][2 * t2][0]);
        float a1 = ex2(sacc[i][2 * t2][1]);
        float a2 = ex2(sacc[i][2 * t2][2]);
        float a3 = ex2(sacc[i][2 * t2][3]);
        float b0 = ex2(sacc[i][2 * t2 + 1][0]);
        float b1 = ex2(sacc[i][2 * t2 + 1][1]);
        float b2 = ex2(sacc[i][2 * t2 + 1][2]);
        float b3 = ex2(sacc[i][2 * t2 + 1][3]);
        u32x4 t;
        t.x = pack2(a0, a1);
        t.y = pack2(a2, a3);
        t.z = pack2(b0, b1);
        t.w = pack2(b2, b3);
        pf[i] = __builtin_bit_cast(bf16x8, t);
      }
      __builtin_amdgcn_s_setprio(1);
      #pragma unroll
      for (int vt = 0; vt < 4; vt++) {
        int row = vt * 16 + l15;
        int c16 = (t2 * 4 + g) ^ (row & 7);
        bf16x8 vv = *(const bf16x8*)(Vlds + row * 128 + c16 * 16);
        oacc[vt][0] = MFMA16(vv, pf[0], oacc[vt][0]);
        oacc[vt][1] = MFMA16(vv, pf[1], oacc[vt][1]);
      }
      sumacc[0] = MFMA16(ones8, pf[0], sumacc[0]);
      sumacc[1] = MFMA16(ones8, pf[1], sumacc[1]);
      __builtin_amdgcn_s_setprio(0);
    }

    // drain global loads (issued ~1000cy ago), commit V regs to next buffer, ONE barrier
    asm volatile("s_waitcnt vmcnt(0)" ::: "memory");
    if (kt + 1 < 32) writeV(cur ^ 1, vreg);
    asm volatile("s_waitcnt lgkmcnt(0)" ::: "memory");
    __builtin_amdgcn_s_barrier();
    __builtin_amdgcn_sched_barrier(0);
  }

  // epilogue: O^T / l -> attn_out [B,S,H*64] bf16 (sumacc replicated over r; col = own qrow)
  #pragma unroll
  for (int i = 0; i < 2; i++) {
    float inv = 1.0f / sumacc[i][0];
    int srow = qt * 128 + w * 32 + i * 16 + l15;
    #pragma unroll
    for (int vt = 0; vt < 4; vt++) {
      bf16x4 o;
      #pragma unroll
      for (int r = 0; r < 4; r++) o[r] = (__bf16)(oacc[vt][i][r] * inv);
      *(bf16x4*)(aout + ((size_t)b * S_ + srow) * 1024 + h * 64 + vt * 16 + g * 4) = o;
    }
  }
}

// ---------------- launch ----------------
extern "C" void kernel_launch(void* const* d_in, const int* in_sizes, int n_in,
                              void* d_out, int out_size, void* d_ws, size_t ws_size,
                              hipStream_t stream) {
  const float* queries = (const float*)d_in[0];
  const float* keys    = (const float*)d_in[1];
  const float* values  = (const float*)d_in[2];
  const int*   mask    = (const int*)d_in[3];
  const float* Wq      = (const float*)d_in[4];
  const float* Wk      = (const float*)d_in[5];
  const float* Wv      = (const float*)d_in[6];
  const float* Wo      = (const float*)d_in[7];

  char* ws = (char*)d_ws;
  __bf16* Xq  = (__bf16*)(ws + 0);          // 16 MB, later reused as attn_out
  __bf16* Xk  = (__bf16*)(ws + 16777216);   // 16 MB
  __bf16* Xv  = (__bf16*)(ws + 33554432);   // 16 MB
  __bf16* Wqb = (__bf16*)(ws + 50331648);   // 2 MB each
  __bf16* Wkb = (__bf16*)(ws + 52428800);
  __bf16* Wvb = (__bf16*)(ws + 54525952);
  __bf16* Wob = (__bf16*)(ws + 56623104);
  __bf16* qp  = (__bf16*)(ws + 58720256);   // 16 MB [B,H,S,64]
  __bf16* kp  = (__bf16*)(ws + 75497472);   // 16 MB [B,H,S,64]
  __bf16* vT  = (__bf16*)(ws + 92274688);   // 16 MB [B,H,64,S]
  uint32_t* bits = (uint32_t*)(ws + 109051904);  // 2 MB
  int* flags     = (int*)(ws + 111149056);       // 4 KB
  __bf16* aout = Xq;  // alias: Xq dead after proj GEMM

  // flags pre-init to all-ones (0xFFFFFFFF truthy for attn's `if(!fl)`); prep atomicAnds 0
  hipMemsetAsync(flags, 0xFF, 4096, stream);

  prep<<<3840, 256, 0, stream>>>(queries, keys, values, Wq, Wk, Wv, Wo,
                                 Xq, Xk, Xv, Wqb, Wkb, Wvb, Wob,
                                 mask, bits, flags);

  gemm_bt<0><<<dim3(8, 64, 3), 256, 0, stream>>>(Xq, Xk, Xv, Wqb, Wkb, Wvb,
                                                 (void*)qp, (void*)kp, (void*)vT);

  attn<<<dim3(16, 64), 256, 0, stream>>>(qp, kp, vT, aout, bits, flags);

  gemm_bt<1><<<dim3(8, 64, 1), 256, 0, stream>>>(aout, nullptr, nullptr, Wob, nullptr, nullptr,
                                                 (void*)d_out, nullptr, nullptr);
}